// Round 15
// baseline (43.054 us; speedup 1.0000x reference)
//
#include <hip/hip_runtime.h>
#include <hip/hip_bf16.h>

typedef _Float16 f16x8 __attribute__((ext_vector_type(8)));
typedef _Float16 f16x4 __attribute__((ext_vector_type(4)));
typedef float    f32x4 __attribute__((ext_vector_type(4)));

constexpr int BB  = 4096;
constexpr int AA  = 64;
constexpr int ED  = 10;
constexpr int P1N = 32, P2N = 128, P3N = 256;
constexpr int PT  = 416;          // = 13 * 32
constexpr int NKS = 13;           // K-steps of 32
constexpr int KSPL = 7;           // k-half split: [0,7) / [7,13)
constexpr int BCH = 32;           // b rows per block
constexpr int NCH = 4;            // a-channels per block (fp16x4 per slot)

// ---------------------------------------------------------------------------
// idxs[p] = (sa*8) | (sb*8)<<10 | (sc*8)<<20  -- BYTE offsets into an f16x4
// row (8 B/slot). Unused factors -> slot 64 (constant 1.0).
// ---------------------------------------------------------------------------
__global__ void build_idx_kernel(
    const int* __restrict__ i1, const int* __restrict__ l1,
    const int* __restrict__ i2, const int* __restrict__ j2,
    const int* __restrict__ l2, const int* __restrict__ m2,
    const int* __restrict__ i3, const int* __restrict__ j3,
    const int* __restrict__ f3, const int* __restrict__ l3,
    const int* __restrict__ m3, const int* __restrict__ g3,
    unsigned* __restrict__ idxs) {
  const int p = threadIdx.x;
  if (p >= PT) return;
  unsigned sa, sb = 64, sc = 64;
  if (p < P1N) {
    sa = i1[p] * 4 + l1[p];
  } else if (p < P1N + P2N) {
    int pp = p - P1N;
    sa = i2[pp] * 4 + l2[pp];
    sb = j2[pp] * 4 + m2[pp];
  } else {
    int pp = p - P1N - P2N;
    sa = i3[pp] * 4 + l3[pp];
    sb = j3[pp] * 4 + m3[pp];
    sc = f3[pp] * 4 + g3[pp];
  }
  idxs[p] = (sa * 8) | ((sb * 8) << 10) | ((sc * 8) << 20);
}

// ---------------------------------------------------------------------------
// B-frag table (fp16): cwb[a][ks][lane][j] = f16( coeff[p] * w[e,k[p],q[p],a] )
// p = ks*32 + (lane>>4)*8 + j, e = lane&15 (0 for e>=10).
// ---------------------------------------------------------------------------
__global__ void build_cwb_kernel(
    const float* __restrict__ w1, const float* __restrict__ w2, const float* __restrict__ w3,
    const float* __restrict__ c1, const float* __restrict__ c2, const float* __restrict__ c3,
    const int* __restrict__ k1, const int* __restrict__ q1,
    const int* __restrict__ k2, const int* __restrict__ q2,
    const int* __restrict__ k3, const int* __restrict__ q3,
    _Float16* __restrict__ cwb) {
  const int a  = blockIdx.x & 63;
  const int ks = blockIdx.x >> 6;   // 0..12
  const int l  = threadIdx.x;       // 0..63
  const int grp = l >> 4, e = l & 15;
  _Float16* dst = cwb + (((size_t)a * NKS + ks) * 64 + l) * 8;
  #pragma unroll
  for (int j = 0; j < 8; ++j) {
    const int p = ks * 32 + grp * 8 + j;
    float v = 0.f;
    if (e < ED) {
      const float* w; float coeff; int k, q, K, Q;
      if (p < P1N)            { w = w1; coeff = c1[p]; k = k1[p]; q = q1[p]; K = 4;  Q = 2; }
      else if (p < P1N + P2N) { int pp = p - P1N;       w = w2; coeff = c2[pp]; k = k2[pp]; q = q2[pp]; K = 16; Q = 4; }
      else                    { int pp = p - P1N - P2N; w = w3; coeff = c3[pp]; k = k3[pp]; q = q3[pp]; K = 32; Q = 6; }
      v = coeff * w[(((size_t)e * K + k) * Q + q) * AA + a];
    }
    dst[j] = (_Float16)v;
  }
}

// ---------------------------------------------------------------------------
// One K-step, pure SSA (r14 body).
// ---------------------------------------------------------------------------
template <int NF, int KS>
__device__ __forceinline__ void kstep(
    const char* __restrict__ rowb, const uint4* __restrict__ ip,
    const f16x8* __restrict__ cw0, const f16x8* __restrict__ cw1,
    const f16x8* __restrict__ cw2, const f16x8* __restrict__ cw3,
    f32x4& ac0, f32x4& ac1, f32x4& ac2, f32x4& ac3) {
  const uint4 iA = ip[KS * 8 + 0];
  const uint4 iB = ip[KS * 8 + 1];
  const f16x8 b0 = cw0[KS * 64];
  const f16x8 b1 = cw1[KS * 64];
  const f16x8 b2 = cw2[KS * 64];
  const f16x8 b3 = cw3[KS * 64];
  const unsigned pks[8] = {iA.x, iA.y, iA.z, iA.w, iB.x, iB.y, iB.z, iB.w};
  f16x8 af0, af1, af2, af3;
  #pragma unroll
  for (int jh = 0; jh < 2; ++jh) {
    f16x4 g0[4], g1[4], g2[4];
    #pragma unroll
    for (int j = 0; j < 4; ++j) {
      const unsigned pk = pks[jh * 4 + j];
      g0[j] = *(const f16x4*)(rowb + (pk & 1023u));
      if (NF >= 2) g1[j] = *(const f16x4*)(rowb + ((pk >> 10) & 1023u));
      if (NF >= 3) g2[j] = *(const f16x4*)(rowb + (pk >> 20));
    }
    #pragma unroll
    for (int j = 0; j < 4; ++j) {
      f16x4 v = g0[j];
      if (NF >= 2) v = v * g1[j];
      if (NF >= 3) v = v * g2[j];
      const int jj = jh * 4 + j;
      af0[jj] = v[0]; af1[jj] = v[1]; af2[jj] = v[2]; af3[jj] = v[3];
    }
  }
  ac0 = __builtin_amdgcn_mfma_f32_16x16x32_f16(af0, b0, ac0, 0, 0, 0);
  ac1 = __builtin_amdgcn_mfma_f32_16x16x32_f16(af1, b1, ac1, 0, 0, 0);
  ac2 = __builtin_amdgcn_mfma_f32_16x16x32_f16(af2, b2, ac2, 0, 0, 0);
  ac3 = __builtin_amdgcn_mfma_f32_16x16x32_f16(af3, b3, ac3, 0, 0, 0);
}

// ---------------------------------------------------------------------------
// Main: block = a-quad x 32 b's; 4 waves = 2 M-tiles x 2 k-halves.
// (256,6): 85-VGPR cap (current body = 60), 18.8 KB LDS -> 6 blocks/CU
// = 24 waves/CU. Per-wave kstep chain halved (6-7 vs 13).
// ---------------------------------------------------------------------------
__global__ __launch_bounds__(256, 6)
void contract_kernel(const float* __restrict__ x, const float* __restrict__ y,
                     const unsigned* __restrict__ idxs,
                     const f16x8* __restrict__ cwb,
                     float* __restrict__ out) {
  __shared__ f16x4 xls[BCH][65];   // slot 64 = {1,1,1,1}; 16.6 KB
  __shared__ float yls[BCH][17];   // e padded to 16 with zeros

  const int t  = threadIdx.x;
  const int a0 = (blockIdx.x & 15) * NCH;
  const int b0 = (blockIdx.x >> 4) * BCH;
  const int wv = t >> 6, l = t & 63, grp = l >> 4, er = l & 15;

  // Cooperative staging: wave wv stages rows [wv*8, wv*8+8). Per iteration
  // lane l covers row wv*8+i*4+(l>>4), slots 4*(l&15)..+3 (float4 loads).
  #pragma unroll
  for (int i = 0; i < 2; ++i) {
    const int row = wv * 8 + i * 4 + (l >> 4);
    const int s   = (l & 15) * 4;
    const float* xb = x + (size_t)(b0 + row) * 4096 + a0 * 64 + s;
    const float4 L0 = *(const float4*)(xb);
    const float4 L1 = *(const float4*)(xb + 64);
    const float4 L2 = *(const float4*)(xb + 128);
    const float4 L3 = *(const float4*)(xb + 192);
    f16x4 v0, v1, v2, v3;
    v0[0] = (_Float16)L0.x; v0[1] = (_Float16)L1.x; v0[2] = (_Float16)L2.x; v0[3] = (_Float16)L3.x;
    v1[0] = (_Float16)L0.y; v1[1] = (_Float16)L1.y; v1[2] = (_Float16)L2.y; v1[3] = (_Float16)L3.y;
    v2[0] = (_Float16)L0.z; v2[1] = (_Float16)L1.z; v2[2] = (_Float16)L2.z; v2[3] = (_Float16)L3.z;
    v3[0] = (_Float16)L0.w; v3[1] = (_Float16)L1.w; v3[2] = (_Float16)L2.w; v3[3] = (_Float16)L3.w;
    xls[row][s + 0] = v0;
    xls[row][s + 1] = v1;
    xls[row][s + 2] = v2;
    xls[row][s + 3] = v3;
  }
  if (l < 8) {
    const int row = wv * 8 + l;
    f16x4 one;
    one[0] = one[1] = one[2] = one[3] = (_Float16)1.0f;
    xls[row][64] = one;
    const float* yb = y + (size_t)(b0 + row) * ED;
    #pragma unroll
    for (int e = 0; e < ED; ++e) yls[row][e] = yb[e];
    #pragma unroll
    for (int e = ED; e < 16; ++e) yls[row][e] = 0.f;
  }
  __syncthreads();

  const int mt = wv & 1;            // M-tile (16 rows)
  const int kh = wv >> 1;           // k-half
  const int r0 = mt * 16;
  const char* __restrict__ rowb = (const char*)&xls[r0 + er][0];
  const f16x8* __restrict__ cw0 = cwb + ((size_t)(a0 + 0) * NKS) * 64 + l;
  const f16x8* __restrict__ cw1 = cwb + ((size_t)(a0 + 1) * NKS) * 64 + l;
  const f16x8* __restrict__ cw2 = cwb + ((size_t)(a0 + 2) * NKS) * 64 + l;
  const f16x8* __restrict__ cw3 = cwb + ((size_t)(a0 + 3) * NKS) * 64 + l;
  const uint4*  __restrict__ ip  = (const uint4*)idxs + grp * 2;

  f32x4 ac0 = {0.f, 0.f, 0.f, 0.f};
  f32x4 ac1 = {0.f, 0.f, 0.f, 0.f};
  f32x4 ac2 = {0.f, 0.f, 0.f, 0.f};
  f32x4 ac3 = {0.f, 0.f, 0.f, 0.f};

  #define STEP(NF, KS) \
    kstep<NF, KS>(rowb, ip, cw0, cw1, cw2, cw3, ac0, ac1, ac2, ac3)
  if (kh == 0) {
    STEP(1, 0);                                      // path 1
    STEP(2, 1); STEP(2, 2); STEP(2, 3); STEP(2, 4);  // path 2
    STEP(3, 5); STEP(3, 6);                          // path 3 head
  } else {
    STEP(3, 7); STEP(3, 8); STEP(3, 9);              // path 3 tail
    STEP(3, 10); STEP(3, 11); STEP(3, 12);
  }
  #undef STEP

  // Combine k-halves via LDS scratch (reuse xls region; stride 17 banks).
  __syncthreads();
  float* scr = (float*)&xls[0][0];
  const int sbase = (mt * 64 + l) * 17;
  if (kh == 1) {
    #pragma unroll
    for (int v = 0; v < 4; ++v) {
      scr[sbase + v + 0]  = ac0[v];
      scr[sbase + v + 4]  = ac1[v];
      scr[sbase + v + 8]  = ac2[v];
      scr[sbase + v + 12] = ac3[v];
    }
  }
  __syncthreads();
  if (kh == 0) {
    #pragma unroll
    for (int v = 0; v < 4; ++v) {
      ac0[v] += scr[sbase + v + 0];
      ac1[v] += scr[sbase + v + 4];
      ac2[v] += scr[sbase + v + 8];
      ac3[v] += scr[sbase + v + 12];
    }
    // Epilogue: D[row = r0+grp*4+v][col = er], y-weight, reduce over e.
    #pragma unroll
    for (int c = 0; c < NCH; ++c) {
      const f32x4 acc = c == 0 ? ac0 : c == 1 ? ac1 : c == 2 ? ac2 : ac3;
      float s0 = acc[0] * yls[r0 + grp * 4 + 0][er];
      float s1 = acc[1] * yls[r0 + grp * 4 + 1][er];
      float s2 = acc[2] * yls[r0 + grp * 4 + 2][er];
      float s3 = acc[3] * yls[r0 + grp * 4 + 3][er];
      #pragma unroll
      for (int m = 1; m < 16; m <<= 1) {
        s0 += __shfl_xor(s0, m);
        s1 += __shfl_xor(s1, m);
        s2 += __shfl_xor(s2, m);
        s3 += __shfl_xor(s3, m);
      }
      if (er < 4) {
        const float sv = er == 0 ? s0 : er == 1 ? s1 : er == 2 ? s2 : s3;
        out[(size_t)(b0 + r0 + grp * 4 + er) * AA + (a0 + c)] = sv;
      }
    }
  }
}

// ---------------------------------------------------------------------------
extern "C" void kernel_launch(void* const* d_in, const int* in_sizes, int n_in,
                              void* d_out, int out_size, void* d_ws, size_t ws_size,
                              hipStream_t stream) {
  const float* x  = (const float*)d_in[0];
  const float* y  = (const float*)d_in[1];
  const float* w1 = (const float*)d_in[2];
  const float* w2 = (const float*)d_in[3];
  const float* w3 = (const float*)d_in[4];
  const float* c1 = (const float*)d_in[5];
  const float* c2 = (const float*)d_in[6];
  const float* c3 = (const float*)d_in[7];
  const int* i1 = (const int*)d_in[8];
  const int* l1 = (const int*)d_in[9];
  const int* k1 = (const int*)d_in[10];
  const int* q1 = (const int*)d_in[11];
  const int* i2 = (const int*)d_in[12];
  const int* j2 = (const int*)d_in[13];
  const int* l2 = (const int*)d_in[14];
  const int* m2 = (const int*)d_in[15];
  const int* k2 = (const int*)d_in[16];
  const int* q2 = (const int*)d_in[17];
  const int* i3 = (const int*)d_in[18];
  const int* j3 = (const int*)d_in[19];
  const int* f3 = (const int*)d_in[20];
  const int* l3 = (const int*)d_in[21];
  const int* m3 = (const int*)d_in[22];
  const int* g3 = (const int*)d_in[23];
  const int* k3 = (const int*)d_in[24];
  const int* q3 = (const int*)d_in[25];

  unsigned*  idxs = (unsigned*)d_ws;                    // 416*4 B
  _Float16*  cwb  = (_Float16*)((char*)d_ws + 4096);    // 832 KB

  build_idx_kernel<<<1, 448, 0, stream>>>(i1, l1, i2, j2, l2, m2,
                                          i3, j3, f3, l3, m3, g3, idxs);
  build_cwb_kernel<<<AA * NKS, 64, 0, stream>>>(w1, w2, w3, c1, c2, c3,
                                                k1, q1, k2, q2, k3, q3, cwb);
  contract_kernel<<<(AA / NCH) * (BB / BCH), 256, 0, stream>>>(
      x, y, idxs, (const f16x8*)cwb, (float*)d_out);
}

// Round 16
// 38.767 us; speedup vs baseline: 1.1106x; 1.1106x over previous
//
#include <hip/hip_runtime.h>
#include <hip/hip_bf16.h>

typedef _Float16 f16x8 __attribute__((ext_vector_type(8)));
typedef _Float16 f16x4 __attribute__((ext_vector_type(4)));
typedef float    f32x4 __attribute__((ext_vector_type(4)));

constexpr int BB  = 4096;
constexpr int AA  = 64;
constexpr int ED  = 10;
constexpr int P1N = 32, P2N = 128, P3N = 256;
constexpr int PT  = 416;          // = 13 * 32
constexpr int NKS = 13;           // K-steps of 32
constexpr int BCH = 64;           // b rows per block
constexpr int NCH = 4;            // a-channels per block (fp16x4 per slot)

// ---------------------------------------------------------------------------
// idxs[p] = (sa*8) | (sb*8)<<10 | (sc*8)<<20  -- BYTE offsets into an f16x4
// row (8 B/slot). Unused factors -> slot 64 (constant 1.0).
// ---------------------------------------------------------------------------
__global__ void build_idx_kernel(
    const int* __restrict__ i1, const int* __restrict__ l1,
    const int* __restrict__ i2, const int* __restrict__ j2,
    const int* __restrict__ l2, const int* __restrict__ m2,
    const int* __restrict__ i3, const int* __restrict__ j3,
    const int* __restrict__ f3, const int* __restrict__ l3,
    const int* __restrict__ m3, const int* __restrict__ g3,
    unsigned* __restrict__ idxs) {
  const int p = threadIdx.x;
  if (p >= PT) return;
  unsigned sa, sb = 64, sc = 64;
  if (p < P1N) {
    sa = i1[p] * 4 + l1[p];
  } else if (p < P1N + P2N) {
    int pp = p - P1N;
    sa = i2[pp] * 4 + l2[pp];
    sb = j2[pp] * 4 + m2[pp];
  } else {
    int pp = p - P1N - P2N;
    sa = i3[pp] * 4 + l3[pp];
    sb = j3[pp] * 4 + m3[pp];
    sc = f3[pp] * 4 + g3[pp];
  }
  idxs[p] = (sa * 8) | ((sb * 8) << 10) | ((sc * 8) << 20);
}

// ---------------------------------------------------------------------------
// B-frag table (fp16): cwb[a][ks][lane][j] = f16( coeff[p] * w[e,k[p],q[p],a] )
// p = ks*32 + (lane>>4)*8 + j, e = lane&15 (0 for e>=10).
// ---------------------------------------------------------------------------
__global__ void build_cwb_kernel(
    const float* __restrict__ w1, const float* __restrict__ w2, const float* __restrict__ w3,
    const float* __restrict__ c1, const float* __restrict__ c2, const float* __restrict__ c3,
    const int* __restrict__ k1, const int* __restrict__ q1,
    const int* __restrict__ k2, const int* __restrict__ q2,
    const int* __restrict__ k3, const int* __restrict__ q3,
    _Float16* __restrict__ cwb) {
  const int a  = blockIdx.x & 63;
  const int ks = blockIdx.x >> 6;   // 0..12
  const int l  = threadIdx.x;       // 0..63
  const int grp = l >> 4, e = l & 15;
  _Float16* dst = cwb + (((size_t)a * NKS + ks) * 64 + l) * 8;
  #pragma unroll
  for (int j = 0; j < 8; ++j) {
    const int p = ks * 32 + grp * 8 + j;
    float v = 0.f;
    if (e < ED) {
      const float* w; float coeff; int k, q, K, Q;
      if (p < P1N)            { w = w1; coeff = c1[p]; k = k1[p]; q = q1[p]; K = 4;  Q = 2; }
      else if (p < P1N + P2N) { int pp = p - P1N;       w = w2; coeff = c2[pp]; k = k2[pp]; q = q2[pp]; K = 16; Q = 4; }
      else                    { int pp = p - P1N - P2N; w = w3; coeff = c3[pp]; k = k3[pp]; q = q3[pp]; K = 32; Q = 6; }
      v = coeff * w[(((size_t)e * K + k) * Q + q) * AA + a];
    }
    dst[j] = (_Float16)v;
  }
}

// ---------------------------------------------------------------------------
// One K-step, pure SSA (r14 body).
// ---------------------------------------------------------------------------
template <int NF, int KS>
__device__ __forceinline__ void kstep(
    const char* __restrict__ rowb, const uint4* __restrict__ ip,
    const f16x8* __restrict__ cw0, const f16x8* __restrict__ cw1,
    const f16x8* __restrict__ cw2, const f16x8* __restrict__ cw3,
    f32x4& ac0, f32x4& ac1, f32x4& ac2, f32x4& ac3) {
  const uint4 iA = ip[KS * 8 + 0];
  const uint4 iB = ip[KS * 8 + 1];
  const f16x8 b0 = cw0[KS * 64];
  const f16x8 b1 = cw1[KS * 64];
  const f16x8 b2 = cw2[KS * 64];
  const f16x8 b3 = cw3[KS * 64];
  const unsigned pks[8] = {iA.x, iA.y, iA.z, iA.w, iB.x, iB.y, iB.z, iB.w};
  f16x8 af0, af1, af2, af3;
  #pragma unroll
  for (int jh = 0; jh < 2; ++jh) {
    f16x4 g0[4], g1[4], g2[4];
    #pragma unroll
    for (int j = 0; j < 4; ++j) {
      const unsigned pk = pks[jh * 4 + j];
      g0[j] = *(const f16x4*)(rowb + (pk & 1023u));
      if (NF >= 2) g1[j] = *(const f16x4*)(rowb + ((pk >> 10) & 1023u));
      if (NF >= 3) g2[j] = *(const f16x4*)(rowb + (pk >> 20));
    }
    #pragma unroll
    for (int j = 0; j < 4; ++j) {
      f16x4 v = g0[j];
      if (NF >= 2) v = v * g1[j];
      if (NF >= 3) v = v * g2[j];
      const int jj = jh * 4 + j;
      af0[jj] = v[0]; af1[jj] = v[1]; af2[jj] = v[2]; af3[jj] = v[3];
    }
  }
  ac0 = __builtin_amdgcn_mfma_f32_16x16x32_f16(af0, b0, ac0, 0, 0, 0);
  ac1 = __builtin_amdgcn_mfma_f32_16x16x32_f16(af1, b1, ac1, 0, 0, 0);
  ac2 = __builtin_amdgcn_mfma_f32_16x16x32_f16(af2, b2, ac2, 0, 0, 0);
  ac3 = __builtin_amdgcn_mfma_f32_16x16x32_f16(af3, b3, ac3, 0, 0, 0);
}

// ---------------------------------------------------------------------------
// Main: r14 structure (block = a-quad x 64 b's; 4 private M-tiles, no
// __syncthreads; float4 staging) + DUAL-CHAIN k-split per wave: chain A
// (ks 0-6) and chain B (ks 7-12) carry separate accumulators and are
// source-interleaved -> two independent dataflow chains the scheduler can
// overlap (no cross-kstep hoisting needed). acc = accA + accB at the end.
// (256,4): 128-VGPR budget (WRITE_SIZE spill sentinel).
// ---------------------------------------------------------------------------
__global__ __launch_bounds__(256, 4)
void contract_kernel(const float* __restrict__ x, const float* __restrict__ y,
                     const unsigned* __restrict__ idxs,
                     const f16x8* __restrict__ cwb,
                     float* __restrict__ out) {
  __shared__ f16x4 xls[BCH][65];   // slot 64 = {1,1,1,1}; 33.3 KB
  __shared__ float yls[BCH][17];   // e padded to 16 with zeros

  const int t  = threadIdx.x;
  const int a0 = (blockIdx.x & 15) * NCH;
  const int b0 = (blockIdx.x >> 4) * BCH;
  const int wv = t >> 6, l = t & 63, grp = l >> 4, er = l & 15;
  const int r0 = wv * 16;          // this wave's private row base

  // Per-wave staging: iteration i covers rows r0+i*4 .. +3; lane l handles
  // row r0+i*4+(l>>4), slots 4*(l&15)..+3. Four float4 loads (one per
  // channel), cvt+transpose to 4 f16x4 slots, 32B contiguous LDS write.
  #pragma unroll
  for (int i = 0; i < 4; ++i) {
    const int row = r0 + i * 4 + (l >> 4);
    const int s   = (l & 15) * 4;
    const float* xb = x + (size_t)(b0 + row) * 4096 + a0 * 64 + s;
    const float4 L0 = *(const float4*)(xb);
    const float4 L1 = *(const float4*)(xb + 64);
    const float4 L2 = *(const float4*)(xb + 128);
    const float4 L3 = *(const float4*)(xb + 192);
    f16x4 v0, v1, v2, v3;
    v0[0] = (_Float16)L0.x; v0[1] = (_Float16)L1.x; v0[2] = (_Float16)L2.x; v0[3] = (_Float16)L3.x;
    v1[0] = (_Float16)L0.y; v1[1] = (_Float16)L1.y; v1[2] = (_Float16)L2.y; v1[3] = (_Float16)L3.y;
    v2[0] = (_Float16)L0.z; v2[1] = (_Float16)L1.z; v2[2] = (_Float16)L2.z; v2[3] = (_Float16)L3.z;
    v3[0] = (_Float16)L0.w; v3[1] = (_Float16)L1.w; v3[2] = (_Float16)L2.w; v3[3] = (_Float16)L3.w;
    xls[row][s + 0] = v0;
    xls[row][s + 1] = v1;
    xls[row][s + 2] = v2;
    xls[row][s + 3] = v3;
  }
  if (l < 16) {
    f16x4 one;
    one[0] = one[1] = one[2] = one[3] = (_Float16)1.0f;
    xls[r0 + l][64] = one;
    const float* yb = y + (size_t)(b0 + r0 + l) * ED;
    #pragma unroll
    for (int e = 0; e < ED; ++e) yls[r0 + l][e] = yb[e];
    #pragma unroll
    for (int e = ED; e < 16; ++e) yls[r0 + l][e] = 0.f;
  }
  // NO __syncthreads: wave reads only its own writes (in-wave lgkmcnt).

  const char* __restrict__ rowb = (const char*)&xls[r0 + er][0];
  const f16x8* __restrict__ cw0 = cwb + ((size_t)(a0 + 0) * NKS) * 64 + l;
  const f16x8* __restrict__ cw1 = cwb + ((size_t)(a0 + 1) * NKS) * 64 + l;
  const f16x8* __restrict__ cw2 = cwb + ((size_t)(a0 + 2) * NKS) * 64 + l;
  const f16x8* __restrict__ cw3 = cwb + ((size_t)(a0 + 3) * NKS) * 64 + l;
  const uint4*  __restrict__ ip  = (const uint4*)idxs + grp * 2;

  // Chain A: ks 0-6.  Chain B: ks 7-12.  Independent accumulators.
  f32x4 a0A = {0.f, 0.f, 0.f, 0.f}, a1A = a0A, a2A = a0A, a3A = a0A;
  f32x4 a0B = a0A, a1B = a0A, a2B = a0A, a3B = a0A;

  #define SA(NF, KS) \
    kstep<NF, KS>(rowb, ip, cw0, cw1, cw2, cw3, a0A, a1A, a2A, a3A)
  #define SB(NF, KS) \
    kstep<NF, KS>(rowb, ip, cw0, cw1, cw2, cw3, a0B, a1B, a2B, a3B)
  SA(1, 0);  SB(3, 7);
  SA(2, 1);  SB(3, 8);
  SA(2, 2);  SB(3, 9);
  SA(2, 3);  SB(3, 10);
  SA(2, 4);  SB(3, 11);
  SA(3, 5);  SB(3, 12);
  SA(3, 6);
  #undef SA
  #undef SB

  const f32x4 ac0 = a0A + a0B;
  const f32x4 ac1 = a1A + a1B;
  const f32x4 ac2 = a2A + a2B;
  const f32x4 ac3 = a3A + a3B;

  // Epilogue: D[row = grp*4+v][col = er], y-weight, 16-lane reduce over e.
  #pragma unroll
  for (int c = 0; c < NCH; ++c) {
    const f32x4 acc = c == 0 ? ac0 : c == 1 ? ac1 : c == 2 ? ac2 : ac3;
    float s0 = acc[0] * yls[r0 + grp * 4 + 0][er];
    float s1 = acc[1] * yls[r0 + grp * 4 + 1][er];
    float s2 = acc[2] * yls[r0 + grp * 4 + 2][er];
    float s3 = acc[3] * yls[r0 + grp * 4 + 3][er];
    #pragma unroll
    for (int m = 1; m < 16; m <<= 1) {
      s0 += __shfl_xor(s0, m);
      s1 += __shfl_xor(s1, m);
      s2 += __shfl_xor(s2, m);
      s3 += __shfl_xor(s3, m);
    }
    if (er < 4) {
      const float sv = er == 0 ? s0 : er == 1 ? s1 : er == 2 ? s2 : s3;
      out[(size_t)(b0 + r0 + grp * 4 + er) * AA + (a0 + c)] = sv;
    }
  }
}

// ---------------------------------------------------------------------------
extern "C" void kernel_launch(void* const* d_in, const int* in_sizes, int n_in,
                              void* d_out, int out_size, void* d_ws, size_t ws_size,
                              hipStream_t stream) {
  const float* x  = (const float*)d_in[0];
  const float* y  = (const float*)d_in[1];
  const float* w1 = (const float*)d_in[2];
  const float* w2 = (const float*)d_in[3];
  const float* w3 = (const float*)d_in[4];
  const float* c1 = (const float*)d_in[5];
  const float* c2 = (const float*)d_in[6];
  const float* c3 = (const float*)d_in[7];
  const int* i1 = (const int*)d_in[8];
  const int* l1 = (const int*)d_in[9];
  const int* k1 = (const int*)d_in[10];
  const int* q1 = (const int*)d_in[11];
  const int* i2 = (const int*)d_in[12];
  const int* j2 = (const int*)d_in[13];
  const int* l2 = (const int*)d_in[14];
  const int* m2 = (const int*)d_in[15];
  const int* k2 = (const int*)d_in[16];
  const int* q2 = (const int*)d_in[17];
  const int* i3 = (const int*)d_in[18];
  const int* j3 = (const int*)d_in[19];
  const int* f3 = (const int*)d_in[20];
  const int* l3 = (const int*)d_in[21];
  const int* m3 = (const int*)d_in[22];
  const int* g3 = (const int*)d_in[23];
  const int* k3 = (const int*)d_in[24];
  const int* q3 = (const int*)d_in[25];

  unsigned*  idxs = (unsigned*)d_ws;                    // 416*4 B
  _Float16*  cwb  = (_Float16*)((char*)d_ws + 4096);    // 832 KB

  build_idx_kernel<<<1, 448, 0, stream>>>(i1, l1, i2, j2, l2, m2,
                                          i3, j3, f3, l3, m3, g3, idxs);
  build_cwb_kernel<<<AA * NKS, 64, 0, stream>>>(w1, w2, w3, c1, c2, c3,
                                                k1, q1, k2, q2, k3, q3, cwb);
  contract_kernel<<<(AA / NCH) * (BB / BCH), 256, 0, stream>>>(
      x, y, idxs, (const f16x8*)cwb, (float*)d_out);
}

// Round 17
// 38.077 us; speedup vs baseline: 1.1307x; 1.0181x over previous
//
#include <hip/hip_runtime.h>
#include <hip/hip_bf16.h>

typedef _Float16 f16x8 __attribute__((ext_vector_type(8)));
typedef _Float16 f16x4 __attribute__((ext_vector_type(4)));
typedef float    f32x4 __attribute__((ext_vector_type(4)));

constexpr int BB  = 4096;
constexpr int AA  = 64;
constexpr int ED  = 10;
constexpr int P1N = 32, P2N = 128, P3N = 256;
constexpr int PT  = 416;          // = 13 * 32
constexpr int NKS = 13;           // K-steps of 32
constexpr int BCH = 64;           // b rows per block
constexpr int NCH = 4;            // a-channels per block (fp16x4 per slot)

// ---------------------------------------------------------------------------
// Merged setup (one launch):
//  blocks 0..831: cwb[aq][ks][lane][ch][8] = f16(coeff[p]*w[e,k[p],q[p],a]),
//    p = ks*32 + (lane>>4)*8 + j, e = lane&15 (0 for e>=10), a = aq*4+ch.
//    -> per kstep, one lane's 4 channel-frags are CONTIGUOUS 64 B (one line).
//  block 832: idxs[p] = (sa*8) | (sb*8)<<10 | (sc*8)<<20 (byte offsets into
//    f16x4 rows; unused factors -> slot 64 = constant 1.0).
// ---------------------------------------------------------------------------
__global__ void build_tables_kernel(
    const float* __restrict__ w1, const float* __restrict__ w2, const float* __restrict__ w3,
    const float* __restrict__ c1, const float* __restrict__ c2, const float* __restrict__ c3,
    const int* __restrict__ k1, const int* __restrict__ q1,
    const int* __restrict__ k2, const int* __restrict__ q2,
    const int* __restrict__ k3, const int* __restrict__ q3,
    const int* __restrict__ i1, const int* __restrict__ l1,
    const int* __restrict__ i2, const int* __restrict__ j2,
    const int* __restrict__ l2, const int* __restrict__ m2,
    const int* __restrict__ i3, const int* __restrict__ j3,
    const int* __restrict__ f3, const int* __restrict__ l3,
    const int* __restrict__ m3, const int* __restrict__ g3,
    _Float16* __restrict__ cwb, unsigned* __restrict__ idxs) {
  if (blockIdx.x == AA * NKS) {
    for (int p = threadIdx.x; p < PT; p += 64) {
      unsigned sa, sb = 64, sc = 64;
      if (p < P1N) {
        sa = i1[p] * 4 + l1[p];
      } else if (p < P1N + P2N) {
        int pp = p - P1N;
        sa = i2[pp] * 4 + l2[pp];
        sb = j2[pp] * 4 + m2[pp];
      } else {
        int pp = p - P1N - P2N;
        sa = i3[pp] * 4 + l3[pp];
        sb = j3[pp] * 4 + m3[pp];
        sc = f3[pp] * 4 + g3[pp];
      }
      idxs[p] = (sa * 8) | ((sb * 8) << 10) | ((sc * 8) << 20);
    }
    return;
  }
  const int a  = blockIdx.x & 63;
  const int ks = blockIdx.x >> 6;   // 0..12
  const int l  = threadIdx.x;       // 0..63
  const int grp = l >> 4, e = l & 15;
  const int aq = a >> 2, ch = a & 3;
  _Float16* dst = cwb + ((((size_t)aq * NKS + ks) * 64 + l) * 4 + ch) * 8;
  #pragma unroll
  for (int j = 0; j < 8; ++j) {
    const int p = ks * 32 + grp * 8 + j;
    float v = 0.f;
    if (e < ED) {
      const float* w; float coeff; int k, q, K, Q;
      if (p < P1N)            { w = w1; coeff = c1[p]; k = k1[p]; q = q1[p]; K = 4;  Q = 2; }
      else if (p < P1N + P2N) { int pp = p - P1N;       w = w2; coeff = c2[pp]; k = k2[pp]; q = q2[pp]; K = 16; Q = 4; }
      else                    { int pp = p - P1N - P2N; w = w3; coeff = c3[pp]; k = k3[pp]; q = q3[pp]; K = 32; Q = 6; }
      v = coeff * w[(((size_t)e * K + k) * Q + q) * AA + a];
    }
    dst[j] = (_Float16)v;
  }
}

// ---------------------------------------------------------------------------
// One K-step, pure SSA. B-frags: 4 contiguous f16x8 (one 64-B cache line).
// ---------------------------------------------------------------------------
template <int NF, int KS>
__device__ __forceinline__ void kstep(
    const char* __restrict__ rowb, const uint4* __restrict__ ip,
    const f16x8* __restrict__ cwq,
    f32x4& ac0, f32x4& ac1, f32x4& ac2, f32x4& ac3) {
  const uint4 iA = ip[KS * 8 + 0];
  const uint4 iB = ip[KS * 8 + 1];
  const f16x8* c = cwq + KS * 256;   // 256 f16x8 per kstep (64 lanes x 4 ch)
  const f16x8 b0 = c[0];
  const f16x8 b1 = c[1];
  const f16x8 b2 = c[2];
  const f16x8 b3 = c[3];
  const unsigned pks[8] = {iA.x, iA.y, iA.z, iA.w, iB.x, iB.y, iB.z, iB.w};
  f16x8 af0, af1, af2, af3;
  #pragma unroll
  for (int jh = 0; jh < 2; ++jh) {
    f16x4 g0[4], g1[4], g2[4];
    #pragma unroll
    for (int j = 0; j < 4; ++j) {
      const unsigned pk = pks[jh * 4 + j];
      g0[j] = *(const f16x4*)(rowb + (pk & 1023u));
      if (NF >= 2) g1[j] = *(const f16x4*)(rowb + ((pk >> 10) & 1023u));
      if (NF >= 3) g2[j] = *(const f16x4*)(rowb + (pk >> 20));
    }
    #pragma unroll
    for (int j = 0; j < 4; ++j) {
      f16x4 v = g0[j];
      if (NF >= 2) v = v * g1[j];
      if (NF >= 3) v = v * g2[j];
      const int jj = jh * 4 + j;
      af0[jj] = v[0]; af1[jj] = v[1]; af2[jj] = v[2]; af3[jj] = v[3];
    }
  }
  ac0 = __builtin_amdgcn_mfma_f32_16x16x32_f16(af0, b0, ac0, 0, 0, 0);
  ac1 = __builtin_amdgcn_mfma_f32_16x16x32_f16(af1, b1, ac1, 0, 0, 0);
  ac2 = __builtin_amdgcn_mfma_f32_16x16x32_f16(af2, b2, ac2, 0, 0, 0);
  ac3 = __builtin_amdgcn_mfma_f32_16x16x32_f16(af3, b3, ac3, 0, 0, 0);
}

// ---------------------------------------------------------------------------
// Main: r16 structure (block = a-quad x 64 b's; 4 private M-tiles, no
// __syncthreads; float4 staging; dual-chain k-split) with the cache-line-
// local cwb layout. (256,4): 128-VGPR budget (WRITE_SIZE spill sentinel).
// ---------------------------------------------------------------------------
__global__ __launch_bounds__(256, 4)
void contract_kernel(const float* __restrict__ x, const float* __restrict__ y,
                     const unsigned* __restrict__ idxs,
                     const f16x8* __restrict__ cwb,
                     float* __restrict__ out) {
  __shared__ f16x4 xls[BCH][65];   // slot 64 = {1,1,1,1}; 33.3 KB
  __shared__ float yls[BCH][17];   // e padded to 16 with zeros

  const int t  = threadIdx.x;
  const int aq = blockIdx.x & 15;
  const int a0 = aq * NCH;
  const int b0 = (blockIdx.x >> 4) * BCH;
  const int wv = t >> 6, l = t & 63, grp = l >> 4, er = l & 15;
  const int r0 = wv * 16;          // this wave's private row base

  // Per-wave staging: iteration i covers rows r0+i*4 .. +3; lane l handles
  // row r0+i*4+(l>>4), slots 4*(l&15)..+3. Four float4 loads (one per
  // channel), cvt+transpose to 4 f16x4 slots, 32B contiguous LDS write.
  #pragma unroll
  for (int i = 0; i < 4; ++i) {
    const int row = r0 + i * 4 + (l >> 4);
    const int s   = (l & 15) * 4;
    const float* xb = x + (size_t)(b0 + row) * 4096 + a0 * 64 + s;
    const float4 L0 = *(const float4*)(xb);
    const float4 L1 = *(const float4*)(xb + 64);
    const float4 L2 = *(const float4*)(xb + 128);
    const float4 L3 = *(const float4*)(xb + 192);
    f16x4 v0, v1, v2, v3;
    v0[0] = (_Float16)L0.x; v0[1] = (_Float16)L1.x; v0[2] = (_Float16)L2.x; v0[3] = (_Float16)L3.x;
    v1[0] = (_Float16)L0.y; v1[1] = (_Float16)L1.y; v1[2] = (_Float16)L2.y; v1[3] = (_Float16)L3.y;
    v2[0] = (_Float16)L0.z; v2[1] = (_Float16)L1.z; v2[2] = (_Float16)L2.z; v2[3] = (_Float16)L3.z;
    v3[0] = (_Float16)L0.w; v3[1] = (_Float16)L1.w; v3[2] = (_Float16)L2.w; v3[3] = (_Float16)L3.w;
    xls[row][s + 0] = v0;
    xls[row][s + 1] = v1;
    xls[row][s + 2] = v2;
    xls[row][s + 3] = v3;
  }
  if (l < 16) {
    f16x4 one;
    one[0] = one[1] = one[2] = one[3] = (_Float16)1.0f;
    xls[r0 + l][64] = one;
    const float* yb = y + (size_t)(b0 + r0 + l) * ED;
    #pragma unroll
    for (int e = 0; e < ED; ++e) yls[r0 + l][e] = yb[e];
    #pragma unroll
    for (int e = ED; e < 16; ++e) yls[r0 + l][e] = 0.f;
  }
  // NO __syncthreads: wave reads only its own writes (in-wave lgkmcnt).

  const char* __restrict__ rowb = (const char*)&xls[r0 + er][0];
  const f16x8* __restrict__ cwq = cwb + (size_t)aq * NKS * 256 + (size_t)l * 4;
  const uint4*  __restrict__ ip  = (const uint4*)idxs + grp * 2;

  // Chain A: ks 0-6.  Chain B: ks 7-12.  Independent accumulators.
  f32x4 a0A = {0.f, 0.f, 0.f, 0.f}, a1A = a0A, a2A = a0A, a3A = a0A;
  f32x4 a0B = a0A, a1B = a0A, a2B = a0A, a3B = a0A;

  #define SA(NF, KS) kstep<NF, KS>(rowb, ip, cwq, a0A, a1A, a2A, a3A)
  #define SB(NF, KS) kstep<NF, KS>(rowb, ip, cwq, a0B, a1B, a2B, a3B)
  SA(1, 0);  SB(3, 7);
  SA(2, 1);  SB(3, 8);
  SA(2, 2);  SB(3, 9);
  SA(2, 3);  SB(3, 10);
  SA(2, 4);  SB(3, 11);
  SA(3, 5);  SB(3, 12);
  SA(3, 6);
  #undef SA
  #undef SB

  const f32x4 ac0 = a0A + a0B;
  const f32x4 ac1 = a1A + a1B;
  const f32x4 ac2 = a2A + a2B;
  const f32x4 ac3 = a3A + a3B;

  // Epilogue: D[row = grp*4+v][col = er], y-weight, 16-lane reduce over e.
  #pragma unroll
  for (int c = 0; c < NCH; ++c) {
    const f32x4 acc = c == 0 ? ac0 : c == 1 ? ac1 : c == 2 ? ac2 : ac3;
    float s0 = acc[0] * yls[r0 + grp * 4 + 0][er];
    float s1 = acc[1] * yls[r0 + grp * 4 + 1][er];
    float s2 = acc[2] * yls[r0 + grp * 4 + 2][er];
    float s3 = acc[3] * yls[r0 + grp * 4 + 3][er];
    #pragma unroll
    for (int m = 1; m < 16; m <<= 1) {
      s0 += __shfl_xor(s0, m);
      s1 += __shfl_xor(s1, m);
      s2 += __shfl_xor(s2, m);
      s3 += __shfl_xor(s3, m);
    }
    if (er < 4) {
      const float sv = er == 0 ? s0 : er == 1 ? s1 : er == 2 ? s2 : s3;
      out[(size_t)(b0 + r0 + grp * 4 + er) * AA + (a0 + c)] = sv;
    }
  }
}

// ---------------------------------------------------------------------------
extern "C" void kernel_launch(void* const* d_in, const int* in_sizes, int n_in,
                              void* d_out, int out_size, void* d_ws, size_t ws_size,
                              hipStream_t stream) {
  const float* x  = (const float*)d_in[0];
  const float* y  = (const float*)d_in[1];
  const float* w1 = (const float*)d_in[2];
  const float* w2 = (const float*)d_in[3];
  const float* w3 = (const float*)d_in[4];
  const float* c1 = (const float*)d_in[5];
  const float* c2 = (const float*)d_in[6];
  const float* c3 = (const float*)d_in[7];
  const int* i1 = (const int*)d_in[8];
  const int* l1 = (const int*)d_in[9];
  const int* k1 = (const int*)d_in[10];
  const int* q1 = (const int*)d_in[11];
  const int* i2 = (const int*)d_in[12];
  const int* j2 = (const int*)d_in[13];
  const int* l2 = (const int*)d_in[14];
  const int* m2 = (const int*)d_in[15];
  const int* k2 = (const int*)d_in[16];
  const int* q2 = (const int*)d_in[17];
  const int* i3 = (const int*)d_in[18];
  const int* j3 = (const int*)d_in[19];
  const int* f3 = (const int*)d_in[20];
  const int* l3 = (const int*)d_in[21];
  const int* m3 = (const int*)d_in[22];
  const int* g3 = (const int*)d_in[23];
  const int* k3 = (const int*)d_in[24];
  const int* q3 = (const int*)d_in[25];

  unsigned*  idxs = (unsigned*)d_ws;                    // 416*4 B
  _Float16*  cwb  = (_Float16*)((char*)d_ws + 4096);    // 832 KB

  build_tables_kernel<<<AA * NKS + 1, 64, 0, stream>>>(
      w1, w2, w3, c1, c2, c3, k1, q1, k2, q2, k3, q3,
      i1, l1, i2, j2, l2, m2, i3, j3, f3, l3, m3, g3, cwb, idxs);
  contract_kernel<<<(AA / NCH) * (BB / BCH), 256, 0, stream>>>(
      x, y, idxs, (const f16x8*)cwb, (float*)d_out);
}

// Round 18
// 36.432 us; speedup vs baseline: 1.1817x; 1.0451x over previous
//
#include <hip/hip_runtime.h>
#include <hip/hip_bf16.h>

typedef _Float16 f16x8 __attribute__((ext_vector_type(8)));
typedef _Float16 f16x4 __attribute__((ext_vector_type(4)));
typedef float    f32x4 __attribute__((ext_vector_type(4)));

constexpr int BB  = 4096;
constexpr int AA  = 64;
constexpr int ED  = 10;
constexpr int P1N = 32, P2N = 128, P3N = 256;
constexpr int PT  = 416;          // = 13 * 32
constexpr int NKS = 13;           // K-steps of 32
constexpr int BCH = 64;           // b rows per block
constexpr int NCH = 4;            // a-channels per block (fp16x4 per slot)

// ---------------------------------------------------------------------------
// Merged setup (one launch):
//  blocks 0..831: cwb[aq][ks][lane][ch][8] = f16(coeff[p]*w[e,k[p],q[p],a]),
//    p = ks*32 + (lane>>4)*8 + j, e = lane&15 (0 for e>=10), a = aq*4+ch.
//  block 832: idxs[p] = (sa*8) | (sb*8)<<10 | (sc*8)<<20 (byte offsets into
//    f16x4 rows; unused factors -> slot 64 = constant 1.0).
// ---------------------------------------------------------------------------
__global__ void build_tables_kernel(
    const float* __restrict__ w1, const float* __restrict__ w2, const float* __restrict__ w3,
    const float* __restrict__ c1, const float* __restrict__ c2, const float* __restrict__ c3,
    const int* __restrict__ k1, const int* __restrict__ q1,
    const int* __restrict__ k2, const int* __restrict__ q2,
    const int* __restrict__ k3, const int* __restrict__ q3,
    const int* __restrict__ i1, const int* __restrict__ l1,
    const int* __restrict__ i2, const int* __restrict__ j2,
    const int* __restrict__ l2, const int* __restrict__ m2,
    const int* __restrict__ i3, const int* __restrict__ j3,
    const int* __restrict__ f3, const int* __restrict__ l3,
    const int* __restrict__ m3, const int* __restrict__ g3,
    _Float16* __restrict__ cwb, unsigned* __restrict__ idxs) {
  if (blockIdx.x == AA * NKS) {
    for (int p = threadIdx.x; p < PT; p += 64) {
      unsigned sa, sb = 64, sc = 64;
      if (p < P1N) {
        sa = i1[p] * 4 + l1[p];
      } else if (p < P1N + P2N) {
        int pp = p - P1N;
        sa = i2[pp] * 4 + l2[pp];
        sb = j2[pp] * 4 + m2[pp];
      } else {
        int pp = p - P1N - P2N;
        sa = i3[pp] * 4 + l3[pp];
        sb = j3[pp] * 4 + m3[pp];
        sc = f3[pp] * 4 + g3[pp];
      }
      idxs[p] = (sa * 8) | ((sb * 8) << 10) | ((sc * 8) << 20);
    }
    return;
  }
  const int a  = blockIdx.x & 63;
  const int ks = blockIdx.x >> 6;   // 0..12
  const int l  = threadIdx.x;       // 0..63
  const int grp = l >> 4, e = l & 15;
  const int aq = a >> 2, ch = a & 3;
  _Float16* dst = cwb + ((((size_t)aq * NKS + ks) * 64 + l) * 4 + ch) * 8;
  #pragma unroll
  for (int j = 0; j < 8; ++j) {
    const int p = ks * 32 + grp * 8 + j;
    float v = 0.f;
    if (e < ED) {
      const float* w; float coeff; int k, q, K, Q;
      if (p < P1N)            { w = w1; coeff = c1[p]; k = k1[p]; q = q1[p]; K = 4;  Q = 2; }
      else if (p < P1N + P2N) { int pp = p - P1N;       w = w2; coeff = c2[pp]; k = k2[pp]; q = q2[pp]; K = 16; Q = 4; }
      else                    { int pp = p - P1N - P2N; w = w3; coeff = c3[pp]; k = k3[pp]; q = q3[pp]; K = 32; Q = 6; }
      v = coeff * w[(((size_t)e * K + k) * Q + q) * AA + a];
    }
    dst[j] = (_Float16)v;
  }
}

// ---------------------------------------------------------------------------
// One K-step, pure SSA. idx from LDS (ds_read_b128, group-broadcast) --
// removes the per-kstep L2 round-trip from the serial dependency chain.
// B-frags: 4 contiguous f16x8 (one 64-B cache line).
// ---------------------------------------------------------------------------
template <int NF, int KS>
__device__ __forceinline__ void kstep(
    const char* __restrict__ rowb, const uint4* ip,
    const f16x8* __restrict__ cwq,
    f32x4& ac0, f32x4& ac1, f32x4& ac2, f32x4& ac3) {
  const uint4 iA = ip[KS * 8 + 0];
  const uint4 iB = ip[KS * 8 + 1];
  const f16x8* c = cwq + KS * 256;   // 256 f16x8 per kstep (64 lanes x 4 ch)
  const f16x8 b0 = c[0];
  const f16x8 b1 = c[1];
  const f16x8 b2 = c[2];
  const f16x8 b3 = c[3];
  const unsigned pks[8] = {iA.x, iA.y, iA.z, iA.w, iB.x, iB.y, iB.z, iB.w};
  f16x8 af0, af1, af2, af3;
  #pragma unroll
  for (int jh = 0; jh < 2; ++jh) {
    f16x4 g0[4], g1[4], g2[4];
    #pragma unroll
    for (int j = 0; j < 4; ++j) {
      const unsigned pk = pks[jh * 4 + j];
      g0[j] = *(const f16x4*)(rowb + (pk & 1023u));
      if (NF >= 2) g1[j] = *(const f16x4*)(rowb + ((pk >> 10) & 1023u));
      if (NF >= 3) g2[j] = *(const f16x4*)(rowb + (pk >> 20));
    }
    #pragma unroll
    for (int j = 0; j < 4; ++j) {
      f16x4 v = g0[j];
      if (NF >= 2) v = v * g1[j];
      if (NF >= 3) v = v * g2[j];
      const int jj = jh * 4 + j;
      af0[jj] = v[0]; af1[jj] = v[1]; af2[jj] = v[2]; af3[jj] = v[3];
    }
  }
  ac0 = __builtin_amdgcn_mfma_f32_16x16x32_f16(af0, b0, ac0, 0, 0, 0);
  ac1 = __builtin_amdgcn_mfma_f32_16x16x32_f16(af1, b1, ac1, 0, 0, 0);
  ac2 = __builtin_amdgcn_mfma_f32_16x16x32_f16(af2, b2, ac2, 0, 0, 0);
  ac3 = __builtin_amdgcn_mfma_f32_16x16x32_f16(af3, b3, ac3, 0, 0, 0);
}

// ---------------------------------------------------------------------------
// Main: r17 structure (block = a-quad x 64 b's; 4 private M-tiles, no
// __syncthreads; float4 staging; dual-chain k-split; line-local cwb) + idx
// table staged in LDS (each wave redundantly writes the full 1.66 KB table:
// identical values -> racing writes benign; in-wave lgkmcnt orders wr->rd).
// (256,4): 128-VGPR budget (WRITE_SIZE spill sentinel). LDS 39.3 KB -> 4/CU.
// ---------------------------------------------------------------------------
__global__ __launch_bounds__(256, 4)
void contract_kernel(const float* __restrict__ x, const float* __restrict__ y,
                     const unsigned* __restrict__ idxs,
                     const f16x8* __restrict__ cwb,
                     float* __restrict__ out) {
  __shared__ f16x4 xls[BCH][65];   // slot 64 = {1,1,1,1}; 33.3 KB
  __shared__ float yls[BCH][17];   // e padded to 16 with zeros
  __shared__ uint4 ils[PT / 4];    // idx table, 1.66 KB

  const int t  = threadIdx.x;
  const int aq = blockIdx.x & 15;
  const int a0 = aq * NCH;
  const int b0 = (blockIdx.x >> 4) * BCH;
  const int wv = t >> 6, l = t & 63, grp = l >> 4, er = l & 15;
  const int r0 = wv * 16;          // this wave's private row base

  // Stage idx table: EACH wave writes all 104 uint4 (values identical
  // across waves -> race-safe without barrier).
  {
    const uint4* gip = (const uint4*)idxs;
    for (int u = l; u < PT / 4; u += 64) ils[u] = gip[u];
  }

  // Per-wave x staging: iteration i covers rows r0+i*4 .. +3; lane l handles
  // row r0+i*4+(l>>4), slots 4*(l&15)..+3. Four float4 loads (one per
  // channel), cvt+transpose to 4 f16x4 slots, 32B contiguous LDS write.
  #pragma unroll
  for (int i = 0; i < 4; ++i) {
    const int row = r0 + i * 4 + (l >> 4);
    const int s   = (l & 15) * 4;
    const float* xb = x + (size_t)(b0 + row) * 4096 + a0 * 64 + s;
    const float4 L0 = *(const float4*)(xb);
    const float4 L1 = *(const float4*)(xb + 64);
    const float4 L2 = *(const float4*)(xb + 128);
    const float4 L3 = *(const float4*)(xb + 192);
    f16x4 v0, v1, v2, v3;
    v0[0] = (_Float16)L0.x; v0[1] = (_Float16)L1.x; v0[2] = (_Float16)L2.x; v0[3] = (_Float16)L3.x;
    v1[0] = (_Float16)L0.y; v1[1] = (_Float16)L1.y; v1[2] = (_Float16)L2.y; v1[3] = (_Float16)L3.y;
    v2[0] = (_Float16)L0.z; v2[1] = (_Float16)L1.z; v2[2] = (_Float16)L2.z; v2[3] = (_Float16)L3.z;
    v3[0] = (_Float16)L0.w; v3[1] = (_Float16)L1.w; v3[2] = (_Float16)L2.w; v3[3] = (_Float16)L3.w;
    xls[row][s + 0] = v0;
    xls[row][s + 1] = v1;
    xls[row][s + 2] = v2;
    xls[row][s + 3] = v3;
  }
  if (l < 16) {
    f16x4 one;
    one[0] = one[1] = one[2] = one[3] = (_Float16)1.0f;
    xls[r0 + l][64] = one;
    const float* yb = y + (size_t)(b0 + r0 + l) * ED;
    #pragma unroll
    for (int e = 0; e < ED; ++e) yls[r0 + l][e] = yb[e];
    #pragma unroll
    for (int e = ED; e < 16; ++e) yls[r0 + l][e] = 0.f;
  }
  // NO __syncthreads: wave reads only its own writes (in-wave lgkmcnt).

  const char* __restrict__ rowb = (const char*)&xls[r0 + er][0];
  const f16x8* __restrict__ cwq = cwb + (size_t)aq * NKS * 256 + (size_t)l * 4;
  const uint4* ip = &ils[grp * 2];

  // Chain A: ks 0-6.  Chain B: ks 7-12.  Independent accumulators.
  f32x4 a0A = {0.f, 0.f, 0.f, 0.f}, a1A = a0A, a2A = a0A, a3A = a0A;
  f32x4 a0B = a0A, a1B = a0A, a2B = a0A, a3B = a0A;

  #define SA(NF, KS) kstep<NF, KS>(rowb, ip, cwq, a0A, a1A, a2A, a3A)
  #define SB(NF, KS) kstep<NF, KS>(rowb, ip, cwq, a0B, a1B, a2B, a3B)
  SA(1, 0);  SB(3, 7);
  SA(2, 1);  SB(3, 8);
  SA(2, 2);  SB(3, 9);
  SA(2, 3);  SB(3, 10);
  SA(2, 4);  SB(3, 11);
  SA(3, 5);  SB(3, 12);
  SA(3, 6);
  #undef SA
  #undef SB

  const f32x4 ac0 = a0A + a0B;
  const f32x4 ac1 = a1A + a1B;
  const f32x4 ac2 = a2A + a2B;
  const f32x4 ac3 = a3A + a3B;

  // Epilogue: D[row = grp*4+v][col = er], y-weight, 16-lane reduce over e.
  #pragma unroll
  for (int c = 0; c < NCH; ++c) {
    const f32x4 acc = c == 0 ? ac0 : c == 1 ? ac1 : c == 2 ? ac2 : ac3;
    float s0 = acc[0] * yls[r0 + grp * 4 + 0][er];
    float s1 = acc[1] * yls[r0 + grp * 4 + 1][er];
    float s2 = acc[2] * yls[r0 + grp * 4 + 2][er];
    float s3 = acc[3] * yls[r0 + grp * 4 + 3][er];
    #pragma unroll
    for (int m = 1; m < 16; m <<= 1) {
      s0 += __shfl_xor(s0, m);
      s1 += __shfl_xor(s1, m);
      s2 += __shfl_xor(s2, m);
      s3 += __shfl_xor(s3, m);
    }
    if (er < 4) {
      const float sv = er == 0 ? s0 : er == 1 ? s1 : er == 2 ? s2 : s3;
      out[(size_t)(b0 + r0 + grp * 4 + er) * AA + (a0 + c)] = sv;
    }
  }
}

// ---------------------------------------------------------------------------
extern "C" void kernel_launch(void* const* d_in, const int* in_sizes, int n_in,
                              void* d_out, int out_size, void* d_ws, size_t ws_size,
                              hipStream_t stream) {
  const float* x  = (const float*)d_in[0];
  const float* y  = (const float*)d_in[1];
  const float* w1 = (const float*)d_in[2];
  const float* w2 = (const float*)d_in[3];
  const float* w3 = (const float*)d_in[4];
  const float* c1 = (const float*)d_in[5];
  const float* c2 = (const float*)d_in[6];
  const float* c3 = (const float*)d_in[7];
  const int* i1 = (const int*)d_in[8];
  const int* l1 = (const int*)d_in[9];
  const int* k1 = (const int*)d_in[10];
  const int* q1 = (const int*)d_in[11];
  const int* i2 = (const int*)d_in[12];
  const int* j2 = (const int*)d_in[13];
  const int* l2 = (const int*)d_in[14];
  const int* m2 = (const int*)d_in[15];
  const int* k2 = (const int*)d_in[16];
  const int* q2 = (const int*)d_in[17];
  const int* i3 = (const int*)d_in[18];
  const int* j3 = (const int*)d_in[19];
  const int* f3 = (const int*)d_in[20];
  const int* l3 = (const int*)d_in[21];
  const int* m3 = (const int*)d_in[22];
  const int* g3 = (const int*)d_in[23];
  const int* k3 = (const int*)d_in[24];
  const int* q3 = (const int*)d_in[25];

  unsigned*  idxs = (unsigned*)d_ws;                    // 416*4 B
  _Float16*  cwb  = (_Float16*)((char*)d_ws + 4096);    // 832 KB

  build_tables_kernel<<<AA * NKS + 1, 64, 0, stream>>>(
      w1, w2, w3, c1, c2, c3, k1, q1, k2, q2, k3, q3,
      i1, l1, i2, j2, l2, m2, i3, j3, f3, l3, m3, g3, cwb, idxs);
  contract_kernel<<<(AA / NCH) * (BB / BCH), 256, 0, stream>>>(
      x, y, idxs, (const f16x8*)cwb, (float*)d_out);
}